// Round 10
// baseline (279.548 us; speedup 1.0000x reference)
//
#include <hip/hip_runtime.h>

typedef unsigned int u32;
typedef unsigned short u16;

typedef __attribute__((ext_vector_type(8))) short short8v;   // 8 x bf16 bits, 16B-aligned
typedef __attribute__((ext_vector_type(4))) float f32x4;

#define AS_GLOBAL __attribute__((address_space(1)))
#define AS_LDS    __attribute__((address_space(3)))

static __device__ __forceinline__ u16 f32_bf16_rne(float f) {
  u32 u = __builtin_bit_cast(u32, f);
  u32 lsb = (u >> 16) & 1u;
  u += 0x7fffu + lsb;
  return (u16)(u >> 16);
}

// ---------------------------------------------------------------------------
// Pass 1: quotient-remainder fake quant, f32 -> bf16 bits.
// One group (GS=128) per 16-lane subgroup; 8 elems/lane.
// base >= 2 always, so reference's sel_mask (base < 1.0) is always false.
// ---------------------------------------------------------------------------
__global__ __launch_bounds__(256) void quant_kernel(
    const float* __restrict__ x, u16* __restrict__ xq) {
  const int tid = blockIdx.x * 256 + threadIdx.x;
  const int grp = tid >> 4;
  const int l   = tid & 15;
  const size_t base_e = (size_t)grp * 128;
  const float* gx = x + base_e;

  float4 v0 = *(const float4*)(gx + l * 4);
  float4 v1 = *(const float4*)(gx + 64 + l * 4);
  float xs[8] = {v0.x, v0.y, v0.z, v0.w, v1.x, v1.y, v1.z, v1.w};

  float mabs = 0.f;
  #pragma unroll
  for (int i = 0; i < 8; ++i) mabs = fmaxf(mabs, fabsf(xs[i]));
  #pragma unroll
  for (int s = 1; s < 16; s <<= 1) mabs = fmaxf(mabs, __shfl_xor(mabs, s, 16));
  mabs = fmaxf(mabs, 1e-8f);

  const float thr = mabs / 7.0f;            // true division: matches np
  float base = 64.f;
  base = (thr <= 32.f) ? 32.f : base;
  base = (thr <= 16.f) ? 16.f : base;
  base = (thr <= 8.f)  ? 8.f  : base;
  base = (thr <= 4.f)  ? 4.f  : base;
  base = (thr <= 2.f)  ? 2.f  : base;
  const float rbase = 1.0f / base;          // exact (power of 2)

  float q[8], r[8];
  float mr = 0.f;
  #pragma unroll
  for (int i = 0; i < 8; ++i) {
    float qq = rintf(xs[i] * rbase);        // == rintf(xs/base), exact scale
    qq = fminf(fmaxf(qq, -7.f), 7.f);
    q[i] = qq;
    r[i] = xs[i] - base * qq;               // exact product, IEEE sub
    mr = fmaxf(mr, fabsf(r[i]));
  }
  #pragma unroll
  for (int s = 1; s < 16; s <<= 1) mr = fmaxf(mr, __shfl_xor(mr, s, 16));
  float rs = fmaxf(mr, 1e-8f) / 7.0f;
  rs = fmaxf(rs, 1e-8f);

  u16 o[8];
  #pragma unroll
  for (int i = 0; i < 8; ++i) {
    float rd = rintf(r[i] / rs);            // IEEE division: matches np
    rd = fminf(fmaxf(rd, -8.f), 7.f) * rs;
    o[i] = f32_bf16_rne(q[i] * base + rd);
  }
  uint2 p0, p1;
  p0.x = (u32)o[0] | ((u32)o[1] << 16);
  p0.y = (u32)o[2] | ((u32)o[3] << 16);
  p1.x = (u32)o[4] | ((u32)o[5] << 16);
  p1.y = (u32)o[6] | ((u32)o[7] << 16);
  *(uint2*)(xq + base_e + l * 4) = p0;
  *(uint2*)(xq + base_e + 64 + l * 4) = p1;
}

// ---------------------------------------------------------------------------
// Pass 2: weight f32 -> bf16 bits.
// ---------------------------------------------------------------------------
__global__ __launch_bounds__(256) void wconv_kernel(
    const float* __restrict__ w, u16* __restrict__ wq) {
  const int i = (blockIdx.x * 256 + threadIdx.x) * 4;
  float4 v = *(const float4*)(w + i);
  uint2 p;
  p.x = (u32)f32_bf16_rne(v.x) | ((u32)f32_bf16_rne(v.y) << 16);
  p.y = (u32)f32_bf16_rne(v.z) | ((u32)f32_bf16_rne(v.w) << 16);
  *(uint2*)(wq + i) = p;
}

// ---------------------------------------------------------------------------
// Pass 3: bf16 MFMA GEMM, PERSISTENT grid=256, 256x256 tile, BK=32,
// TRIPLE-buffered LDS (96 KiB), ONE barrier per K-step.
//
// ROUND-10 RATIONALE: r8 ablation showed the 8-barrier/K-step skeleton
// (barrier+setprio+MFMA, no memory ops) costs ~5100 cyc/K-step vs the
// 2483-cyc MFMA floor -- barrier cadence is 77% of the cost. This
// structure pays 1 barrier per K-step (BK=32: 1242 cyc MFMA floor).
//
// Hazard ledger (verified):
//  - stage(t+2) -> buf[(t+2)%3] == buf[(t-1)%3], overwrites tile t-1.
//    All waves' reads of tile t-1 completed before barrier(t-1)
//    (lgkmcnt(0) precedes every barrier); stage(t+2) is issued after
//    barrier(t-1) in program order => no DMA/read race.
//  - vmcnt(4) at iter t: queue = [stage(t+1) 4, stage(t+2) 4] -> drains
//    stage(t+1) exactly; barrier makes tile t+1 collectively visible.
//  - prologue stages tile0+tile1 (8 loads), vmcnt(4) drains tile0.
//  - epilogue stores pollute vmcnt once per 32 steps (drained by the
//    next vmcnt(4)); accepted, same as prior rounds.
//  - setprio REMOVED: barrier-lockstep == m190 regime (setprio negative).
//
// LDS map (16B units): A bufs at {0,1024,2048}, B at {3072,4096,5120}.
// In-buffer: row*4 + (slot ^ ((row>>1)&3)); rows are 64B (32 cols bf16).
// DMA dest linear; global source pre-swizzled (kslot = (lane&3)^((lane>>3)&3)).
// Read swizzle quad^((l16>>1)&3) -> bank-group floor (measured-0-conflict
// pattern from rounds 1-9, identical row-stride algebra).
// ---------------------------------------------------------------------------
#define BM 256
#define BN 256
#define BK 32

__global__ __launch_bounds__(512, 2) void gemm_kernel(
    const u16* __restrict__ A, const u16* __restrict__ B,
    const float* __restrict__ bias, float* __restrict__ out,
    int M, int N, int K) {
  __shared__ short8v ldsv[6144];   // 96 KiB, 16B units

  const int tid  = threadIdx.x;
  const int w    = tid >> 6;
  const int lane = tid & 63;
  const int l16  = lane & 15;
  const int quad = lane >> 4;

  const int xcd = blockIdx.x & 7;
  const int idx = blockIdx.x >> 3;            // 0..31
  const int n0  = (idx & 3) * BN;
  const int mtl = idx >> 2;                   // 0..7
  const int mtb = xcd * 32 + mtl;
  const int wm = (w >> 2) * 128, wn = (w & 3) * 64;

  // fragment read index (16B units): row*4 + swizzled slot
  const int slotsw = quad ^ ((l16 >> 1) & 3);
  const int aidx = (wm + l16) * 4 + slotsw;
  const int bidx = (wn + l16) * 4 + slotsw;

  const int NTOT = (K / BK) * 4;              // 128 K-steps, 4 segments of 32
  auto m0_of = [&](int u) { return (mtb + 8 * (u >> 5)) * BM; };

  // stage one 16KB panel (256 rows x 32 cols bf16): 2 gload_lds dwordx4/thread
  auto stage_panel = [&](const u16* __restrict__ G, int base_u, int r0, int k0) {
    #pragma unroll
    for (int i = 0; i < 2; ++i) {
      const int c = w * 2 + i;                       // 16 chunks of 1 KiB
      const int row = c * 16 + (lane >> 2);
      const int kslot = (lane & 3) ^ ((lane >> 3) & 3);   // pre-swizzled src
      const u16* g = G + (size_t)(r0 + row) * K + (k0 + kslot * 8);
      __builtin_amdgcn_global_load_lds((const AS_GLOBAL u32*)(const void*)g,
          (AS_LDS u32*)(void*)((char*)ldsv + (size_t)base_u * 16 + c * 1024),
          16, 0, 0);
    }
  };

  f32x4 acc[8][4];
  #pragma unroll
  for (int f = 0; f < 8; ++f)
    #pragma unroll
    for (int g = 0; g < 4; ++g)
      acc[f][g] = (f32x4){0.f, 0.f, 0.f, 0.f};

  short8v aA[8], bb[4];

  // rotating buffer bases (16B units): cur = tile t, nxt = t+1, nx2 = t+2
  int curA = 0, nxtA = 1024, nx2A = 2048;

  // prologue: stage tile0 + tile1; drain tile0; barrier
  stage_panel(A, 0,    m0_of(0), 0);
  stage_panel(B, 3072, n0,       0);
  stage_panel(A, 1024, m0_of(1), BK);
  stage_panel(B, 4096, n0,       BK);
  asm volatile("s_waitcnt vmcnt(4)");
  __builtin_amdgcn_s_barrier();

  for (int t = 0; t < NTOT; ++t) {
    // stage tile t+2 into the buffer slot holding tile t-1 (safe: reads of
    // t-1 completed before barrier(t-1), which precedes this in program order)
    if (t + 2 < NTOT)  {
      stage_panel(A, nx2A,        m0_of(t + 2), ((t + 2) & 31) * BK);
      stage_panel(B, nx2A + 3072, n0,           ((t + 2) & 31) * BK);
    }

    // read tile t fragments (12 ds_read_b128) + 32 independent MFMAs;
    // compiler interleaves via counted lgkmcnt
    #pragma unroll
    for (int f = 0; f < 8; ++f) aA[f] = ldsv[curA + f * 64 + aidx];
    #pragma unroll
    for (int g = 0; g < 4; ++g) bb[g] = ldsv[curA + 3072 + g * 64 + bidx];

    #pragma unroll
    for (int f = 0; f < 8; ++f)
      #pragma unroll
      for (int g = 0; g < 4; ++g)
        acc[f][g] = __builtin_amdgcn_mfma_f32_16x16x32_bf16(
            aA[f], bb[g], acc[f][g], 0, 0, 0);

    // my reads of buf[cur] complete before the barrier; tile t+1's DMA drained
    asm volatile("s_waitcnt lgkmcnt(0)");
    if (t + 2 < NTOT) asm volatile("s_waitcnt vmcnt(4)");
    else              asm volatile("s_waitcnt vmcnt(0)");
    __builtin_amdgcn_s_barrier();

    // rotate buffers
    const int tmp = curA; curA = nxtA; nxtA = nx2A; nx2A = tmp;

    // segment epilogue: flush acc, zero, keep streaming
    if ((t & 31) == 31) {
      const int m0 = m0_of(t);
      #pragma unroll
      for (int g = 0; g < 4; ++g) {
        const int col = n0 + wn + g * 16 + l16;
        const float bv = bias[col];
        #pragma unroll
        for (int f = 0; f < 8; ++f) {
          const int r0 = m0 + wm + f * 16 + quad * 4;
          #pragma unroll
          for (int j = 0; j < 4; ++j)
            out[(size_t)(r0 + j) * N + col] = acc[f][g][j] + bv;
        }
      }
      #pragma unroll
      for (int f = 0; f < 8; ++f)
        #pragma unroll
        for (int g = 0; g < 4; ++g)
          acc[f][g] = (f32x4){0.f, 0.f, 0.f, 0.f};
    }
  }
}

// ---------------------------------------------------------------------------
extern "C" void kernel_launch(void* const* d_in, const int* in_sizes, int n_in,
                              void* d_out, int out_size, void* d_ws, size_t ws_size,
                              hipStream_t stream) {
  const float* x    = (const float*)d_in[0];   // [8,8192,1024] f32
  const float* wgt  = (const float*)d_in[1];   // [1024,1024] f32
  const float* bias = (const float*)d_in[2];   // [1024] f32
  float* out = (float*)d_out;                  // [8,8192,1024] f32

  const int K = 1024, N = 1024;
  const int M = in_sizes[0] / K;               // 65536

  u16* xq = (u16*)d_ws;                        // 128 MiB bf16
  u16* wq = xq + (size_t)M * K;                // 2 MiB bf16

  const int ngroups = (M * K) / 128;
  quant_kernel<<<ngroups / 16, 256, 0, stream>>>(x, xq);
  wconv_kernel<<<(N * K) / 1024, 256, 0, stream>>>(wgt, wq);
  gemm_kernel<<<256, 512, 0, stream>>>(xq, wq, bias, out, M, N, K);
}